// Round 10
// baseline (180.298 us; speedup 1.0000x reference)
//
#include <hip/hip_runtime.h>

// ---------------------------------------------------------------------------
// TPA attention, factorized to GQA flash attention.
// B=1, S=2048, HID=2048, H=16, KVH=8, D=128, QR=6, KR=2, VR=2
// ---------------------------------------------------------------------------

constexpr int SEQ   = 2048;
constexpr int HIDN  = 2048;
constexpr int NHEAD = 16;
constexpr int NKVH  = 8;
constexpr int DH    = 128;
constexpr int NCOLS = 1408;   // 96 Aq | 16 Ak | 16 Av | 768 Bq | 256 Bk | 256 Bv

typedef __bf16 bf16x8 __attribute__((ext_vector_type(8)));
typedef float  f32x4  __attribute__((ext_vector_type(4)));

#define MFMA(a, b, c) __builtin_amdgcn_mfma_f32_16x16x32_bf16((a), (b), (c), 0, 0, 0)

__device__ __forceinline__ void gload_lds16(const void* g, void* l) {
  __builtin_amdgcn_global_load_lds(
      (const __attribute__((address_space(1))) void*)g,
      (__attribute__((address_space(3))) void*)l, 16, 0, 0);
}

// ---- fused prep: hidden cvt + W_all^T transpose + Wo^T transpose ----------

__global__ __launch_bounds__(256) void k_prep(
    const float* __restrict__ hidden,
    const float* __restrict__ WAq, const float* __restrict__ WAk,
    const float* __restrict__ WAv, const float* __restrict__ WBq,
    const float* __restrict__ WBk, const float* __restrict__ WBv,
    const float* __restrict__ Wo,
    __bf16* __restrict__ hid_bf, __bf16* __restrict__ WT,
    __bf16* __restrict__ WoT) {
  const int bid = blockIdx.x;
  if (bid < 2048) {                       // ---- hidden f32 -> bf16, x8
    const int i = (bid * 256 + threadIdx.x) * 8;
    f32x4 a = *(const f32x4*)(hidden + i);
    f32x4 b = *(const f32x4*)(hidden + i + 4);
    bf16x8 v;
#pragma unroll
    for (int j = 0; j < 4; j++) { v[j] = (__bf16)a[j]; v[4 + j] = (__bf16)b[j]; }
    *(bf16x8*)(hid_bf + i) = v;
  } else if (bid < 2048 + 44 * 64) {      // ---- W_all^T [1408][2048]
    const int t = bid - 2048;
    const int bc = (t % 44) * 32, bk = (t / 44) * 32;
    __shared__ float tl[32][33];
    const int tx = threadIdx.x & 31, ty = threadIdx.x >> 5;  // ty 0..7
    const int c = bc + tx;
#pragma unroll
    for (int j = 0; j < 32; j += 8) {
      const int k = bk + ty + j;
      float v;
      if (c < 96)        v = WAq[k * 96 + c];
      else if (c < 112)  v = WAk[k * 16 + (c - 96)];
      else if (c < 128)  v = WAv[k * 16 + (c - 112)];
      else if (c < 896)  v = WBq[k * 768 + (c - 128)];
      else if (c < 1152) v = WBk[k * 256 + (c - 896)];
      else               v = WBv[k * 256 + (c - 1152)];
      tl[ty + j][tx] = v;                 // tl[k-local][c-local]
    }
    __syncthreads();
#pragma unroll
    for (int j = 0; j < 32; j += 8)
      WT[(size_t)(bc + ty + j) * HIDN + bk + tx] = (__bf16)tl[tx][ty + j];
  } else {                                // ---- Wo^T [2048][2048]
    const int t = bid - (2048 + 44 * 64);
    const int bn = (t % 64) * 32, bk = (t / 64) * 32;
    __shared__ float tl[32][33];
    const int tx = threadIdx.x & 31, ty = threadIdx.x >> 5;
#pragma unroll
    for (int j = 0; j < 32; j += 8)
      tl[ty + j][tx] = Wo[(size_t)(bk + ty + j) * HIDN + bn + tx];
    __syncthreads();
#pragma unroll
    for (int j = 0; j < 32; j += 8)
      WoT[(size_t)(bn + ty + j) * HIDN + bk + tx] = (__bf16)tl[tx][ty + j];
  }
}

// ---- GEMM: C[M][N] = A[M][K] * BT[N][K]^T, bf16 in, f32 out ---------------
// 128(M)x64(N) tile, 4 waves (2x2), BK=32, 4-deep counted-vmcnt pipeline
// (unchanged from R9). NEW: 2D XCD region swizzle — all 64 blocks of an XCD
// are co-resident, so the 1D chunk swizzle's per-XCD working set (2 A-row-
// blocks + ALL of B = 9.4MB) thrashes the 4MB L2. An (ny/2)x(nx/4) region
// per XCD cuts it to 8x0.5 + 8x0.25 = 6MB. Applied when divisibility holds
// (out GEMM 32x16); proj (22x16) falls back to the chunk swizzle.

__global__ __launch_bounds__(256) void k_gemm_bt(const __bf16* __restrict__ A,
                                                 const __bf16* __restrict__ BT,
                                                 float* __restrict__ C,
                                                 int M, int N, int K) {
  __shared__ __bf16 As[4][4096];  // [buf][128 rows][32 k] linear
  __shared__ __bf16 Bs[4][2048];  // [buf][64 cols][32 k] linear
  const int tid = threadIdx.x;
  const int w = tid >> 6, lane = tid & 63;
  const int lhi = lane >> 4, llo = lane & 15;
  const int wr = w >> 1, wc = w & 1;

  const int nx = gridDim.x, ny = gridDim.y;
  const int id = blockIdx.y * nx + blockIdx.x;
  int brow, bcol;
  if (((ny & 1) == 0) && ((nx & 3) == 0)) {
    // 2D region per XCD: (ny/2) rows x (nx/4) cols
    const int g = id & 7, k = id >> 3;
    const int rows = ny >> 1, cols = nx >> 2;
    const int rg = g >> 2, cg = g & 3;
    const int r = k % rows, c = k / rows;
    brow = (rg * rows + r) * 128;
    bcol = (cg * cols + c) * 64;
  } else {
    const int cpx = (nx * ny) >> 3;
    const int sid = (id & 7) * cpx + (id >> 3);
    brow = (sid / nx) * 128;
    bcol = (sid % nx) * 64;
  }

  const int rA = lane >> 2, kA = (lane & 3) * 8;  // lane -> (row-in-seg, k-seg)
  const int nt = K >> 5;

  f32x4 acc[4][2];
#pragma unroll
  for (int m = 0; m < 4; m++)
#pragma unroll
    for (int n = 0; n < 2; n++) acc[m][n] = (f32x4){0.f, 0.f, 0.f, 0.f};

  auto stage = [&](int t) {              // 3 gload_lds per wave
    const int buf = t & 3;
    const int k0 = t * 32;
#pragma unroll
    for (int i = 0; i < 2; i++) {
      int seg = w * 2 + i;               // 8 segs of 1KB for A
      int row = seg * 16 + rA;
      gload_lds16(A + (size_t)(brow + row) * K + k0 + kA, &As[buf][seg * 512]);
    }
    gload_lds16(BT + (size_t)(bcol + w * 16 + rA) * K + k0 + kA, &Bs[buf][w * 512]);
  };

  stage(0); stage(1); stage(2);                      // nt >= 4 always here
  asm volatile("s_waitcnt vmcnt(6)" ::: "memory");   // tile 0 landed
  __builtin_amdgcn_s_barrier();

  for (int t = 0; t < nt; t++) {
    if (t + 3 < nt) stage(t + 3);
    const int buf = t & 3;
    bf16x8 af[4], bfr[2];
#pragma unroll
    for (int m = 0; m < 4; m++)
      af[m] = *(const bf16x8*)&As[buf][(wr * 64 + m * 16 + llo) * 32 + lhi * 8];
#pragma unroll
    for (int n = 0; n < 2; n++)
      bfr[n] = *(const bf16x8*)&Bs[buf][(wc * 32 + n * 16 + llo) * 32 + lhi * 8];
#pragma unroll
    for (int m = 0; m < 4; m++)
#pragma unroll
      for (int n = 0; n < 2; n++) acc[m][n] = MFMA(af[m], bfr[n], acc[m][n]);
    const int rem = nt - 2 - t;          // stages in flight beyond t+1
    if (rem >= 2)      asm volatile("s_waitcnt vmcnt(6)" ::: "memory");
    else if (rem == 1) asm volatile("s_waitcnt vmcnt(3)" ::: "memory");
    else               asm volatile("s_waitcnt vmcnt(0)" ::: "memory");
    __builtin_amdgcn_s_barrier();
  }

#pragma unroll
  for (int m = 0; m < 4; m++)
#pragma unroll
    for (int n = 0; n < 2; n++) {
      int r0 = brow + wr * 64 + m * 16 + lhi * 4;
      int c0 = bcol + wc * 32 + n * 16 + llo;
#pragma unroll
      for (int r = 0; r < 4; r++) C[(size_t)(r0 + r) * N + c0] = acc[m][n][r];
    }
}

// ---- build Q/K/Vt from projections (rope + rank contraction) --------------

__global__ __launch_bounds__(128) void k_build_qkv(const float* __restrict__ P,
                                                   const float* __restrict__ cosT,
                                                   const float* __restrict__ sinT,
                                                   __bf16* __restrict__ Qo,
                                                   __bf16* __restrict__ Ko,
                                                   __bf16* __restrict__ Vto) {
  const int q = blockIdx.x, d = threadIdx.x;  // 128 threads
  __shared__ float Ash[128];                  // Aq(96) | Ak(16) | Av(16)
  const float* row = P + (size_t)q * NCOLS;
  Ash[d] = row[d];
  __syncthreads();
  const int m2 = (d >> 1) * 2;
  const bool odd = d & 1;
  const float c = cosT[q * 64 + (d >> 1)];
  const float s = sinT[q * 64 + (d >> 1)];

  float qacc[16];
#pragma unroll
  for (int h = 0; h < 16; h++) qacc[h] = 0.f;
#pragma unroll
  for (int r = 0; r < 6; r++) {
    float xe = row[128 + r * 128 + m2];
    float xo = row[128 + r * 128 + m2 + 1];
    float br = odd ? (xe * s + xo * c) : (xe * c - xo * s);
#pragma unroll
    for (int h = 0; h < 16; h++) qacc[h] += Ash[h * 6 + r] * br;
  }
#pragma unroll
  for (int h = 0; h < 16; h++)
    Qo[((size_t)h * SEQ + q) * DH + d] = (__bf16)(qacc[h] * 0.08838834764831845f);

  float kacc[8];
#pragma unroll
  for (int g = 0; g < 8; g++) kacc[g] = 0.f;
#pragma unroll
  for (int ss = 0; ss < 2; ss++) {
    float xe = row[896 + ss * 128 + m2];
    float xo = row[896 + ss * 128 + m2 + 1];
    float bs = odd ? (xe * s + xo * c) : (xe * c - xo * s);
#pragma unroll
    for (int g = 0; g < 8; g++) kacc[g] += Ash[96 + g * 2 + ss] * bs;
  }
#pragma unroll
  for (int g = 0; g < 8; g++)
    Ko[((size_t)g * SEQ + q) * DH + d] = (__bf16)kacc[g];

  float vacc[8];
#pragma unroll
  for (int g = 0; g < 8; g++) vacc[g] = 0.f;
#pragma unroll
  for (int u = 0; u < 2; u++) {
    float vu = row[1152 + u * 128 + d];
#pragma unroll
    for (int g = 0; g < 8; g++) vacc[g] += Ash[112 + g * 2 + u] * vu;
  }
#pragma unroll
  for (int g = 0; g < 8; g++)
    Vto[((size_t)g * DH + d) * SEQ + q] = (__bf16)vacc[g];
}

// ---- flash attention, split-KV parts=2, LDS-staged, XCD-affine ------------
// NEW decode: within XCD g, block j lands on CU (j mod 32) (sequential fill).
// Pass a = j>>5, b = j&31: bqi = (a<2) ? b : 31-b; (hh,p) per pass so that
// every CU's 4 co-resident blocks total EXACTLY 66 tile-units (R6's
// heavy-first gave 80..52 — the 21% straggler CU was the measured VALUBusy
// gap). Bijective over (bqi, hh, p).

__global__ __launch_bounds__(256) void k_attn(const __bf16* __restrict__ Q,
                                              const __bf16* __restrict__ Kc,
                                              const __bf16* __restrict__ Vt,
                                              float* __restrict__ AOf0,
                                              float* __restrict__ AOf1,
                                              float* __restrict__ Ls) {
  const int raw = blockIdx.x;          // 0..1023
  const int g = raw & 7;               // XCD affinity
  const int j = raw >> 3;              // 0..127
  const int a = j >> 5, b = j & 31;    // pass, CU slot
  const int bqi = (a < 2) ? b : 31 - b;
  const int hh = a & 1;
  const int p = ((a + 1) >> 1) & 1;    // pass 0,3 -> part 0; 1,2 -> part 1
  const int h = g * 2 + hh;
  const int w = threadIdx.x >> 6, lane = threadIdx.x & 63;
  const int lhi = lane >> 4, llo = lane & 15;
  const int q0 = bqi * 64 + w * 16;
  const int t0 = p * (bqi + 1), t1 = t0 + bqi + 1;  // half the causal tiles

  __shared__ __bf16 KVs[2][8192];    // 8KB K (32x128 swz) | 8KB V (128x32 swz)
  __shared__ __bf16 Plds[4][512];    // per-wave 16x32 P tile, swizzled

  const __bf16* Qh = Q  + (size_t)h * SEQ * DH;
  const __bf16* Kg = Kc + (size_t)g * SEQ * DH;
  const __bf16* Vg = Vt + (size_t)g * DH * SEQ;
  __bf16* Pl = Plds[w];
  float* AOc = p ? AOf1 : AOf0;

  bf16x8 aq[4];
#pragma unroll
  for (int c = 0; c < 4; c++)
    aq[c] = *(const bf16x8*)&Qh[(size_t)(q0 + llo) * DH + c * 32 + lhi * 8];

  f32x4 oacc[8];
  float lsum[4] = {0.f, 0.f, 0.f, 0.f};
#pragma unroll
  for (int n = 0; n < 8; n++) oacc[n] = (f32x4){0.f, 0.f, 0.f, 0.f};

  // stage one 32-key tile: waves 0-1 stage K (512 16B chunks, swizzled
  // source so linear LDS dest + swizzled read match), waves 2-3 stage V.
  auto stage = [&](int kb, int buf) {
    __bf16* L = KVs[buf];
    if (w < 2) {
#pragma unroll
      for (int u = 0; u < 4; u++) {
        int c = w * 256 + u * 64 + lane;
        int row = c >> 4, jj = c & 15;
        gload_lds16(Kg + (size_t)(kb + row) * DH + ((jj ^ (row & 7)) * 8),
                    L + (w * 256 + u * 64) * 8);
      }
    } else {
#pragma unroll
      for (int u = 0; u < 4; u++) {
        int c = (w - 2) * 256 + u * 64 + lane;
        int d = c >> 2, jj = c & 3;
        gload_lds16(Vg + (size_t)d * SEQ + kb + ((jj ^ ((d >> 1) & 3)) * 8),
                    L + 4096 + ((w - 2) * 256 + u * 64) * 8);
      }
    }
  };

  stage(t0 * 32, t0 & 1);
  for (int t = t0; t < t1; t++) {
    const int kb = t * 32;
    const int buf = t & 1;
    if (t + 1 < t1) {
      stage(kb + 32, buf ^ 1);
      asm volatile("s_waitcnt vmcnt(4)" ::: "memory");  // cur tile staged
    } else {
      asm volatile("s_waitcnt vmcnt(0)" ::: "memory");
    }
    __builtin_amdgcn_s_barrier();
    if (kb <= q0 + 15) {   // wave-uniform skip of fully-masked tiles
      const __bf16* Kl = KVs[buf];
      const __bf16* Vl = KVs[buf] + 4096;
      f32x4 s0 = {0.f, 0.f, 0.f, 0.f}, s1 = {0.f, 0.f, 0.f, 0.f};
#pragma unroll
      for (int c = 0; c < 4; c++) {
        const int row0 = llo, row1 = 16 + llo;
        bf16x8 k0 = *(const bf16x8*)((const char*)Kl + row0 * 256 +
                                     ((c * 64 + lhi * 16) ^ ((row0 & 7) << 4)));
        bf16x8 k1 = *(const bf16x8*)((const char*)Kl + row1 * 256 +
                                     ((c * 64 + lhi * 16) ^ ((row1 & 7) << 4)));
        s0 = MFMA(aq[c], k0, s0);
        s1 = MFMA(aq[c], k1, s1);
      }
#pragma unroll
      for (int r = 0; r < 4; r++) {
        const int qrow = q0 + lhi * 4 + r;
        const int rho = lhi * 4 + r;
        // w = exp(50*tanh(v/50)) = exp2(72.135 - 144.27/(e^{v/25}+1));
        // range [e^-50, e^50] — f32-safe, exact softmax after normalize.
        float t0e = exp2f(s0[r] * 0.057707802f);
        float t1e = exp2f(s1[r] * 0.057707802f);
        float p0 = exp2f(72.134752f - 144.269504f * __builtin_amdgcn_rcpf(t0e + 1.f));
        float p1 = exp2f(72.134752f - 144.269504f * __builtin_amdgcn_rcpf(t1e + 1.f));
        if (kb + llo > qrow) p0 = 0.f;
        if (kb + 16 + llo > qrow) p1 = 0.f;
        lsum[r] += p0 + p1;
        const int sw = ((rho >> 1) & 3) << 4;
        *(__bf16*)((char*)Pl + rho * 64 + ((llo * 2) ^ sw))      = (__bf16)p0;
        *(__bf16*)((char*)Pl + rho * 64 + ((llo * 2 + 32) ^ sw)) = (__bf16)p1;
      }
      bf16x8 pa = *(const bf16x8*)((const char*)Pl + llo * 64 +
                                   ((lhi * 16) ^ (((llo >> 1) & 3) << 4)));
#pragma unroll
      for (int n = 0; n < 8; n++) {
        const int d = n * 16 + llo;
        bf16x8 vf = *(const bf16x8*)((const char*)Vl + d * 64 +
                                     ((lhi * 16) ^ (((d >> 1) & 3) << 4)));
        oacc[n] = MFMA(pa, vf, oacc[n]);
      }
    }
    asm volatile("" ::: "memory");
    __builtin_amdgcn_s_barrier();
  }

#pragma unroll
  for (int r = 0; r < 4; r++) {
    float tsum = lsum[r];
    tsum += __shfl_xor(tsum, 1);
    tsum += __shfl_xor(tsum, 2);
    tsum += __shfl_xor(tsum, 4);
    tsum += __shfl_xor(tsum, 8);
    const int qrow = q0 + lhi * 4 + r;
    if (llo == 0) Ls[((size_t)p * NHEAD + h) * SEQ + qrow] = tsum;
#pragma unroll
    for (int n = 0; n < 8; n++)
      AOc[(size_t)qrow * HIDN + h * DH + n * 16 + llo] = oacc[n][r];
  }
}

// ---- merge split-KV partials, normalize, cast to bf16 ---------------------

__global__ __launch_bounds__(256) void k_norm(const float* __restrict__ A0,
                                              const float* __restrict__ A1,
                                              const float* __restrict__ Ls,
                                              __bf16* __restrict__ AO) {
  const int i = (blockIdx.x * 256 + threadIdx.x) * 4;  // 4M elems, f32x4
  const int q = i >> 11, h = (i & 2047) >> 7;
  const float inv = 1.f / (Ls[h * SEQ + q] + Ls[(NHEAD + h) * SEQ + q]);
  f32x4 a = *(const f32x4*)(A0 + i);
  f32x4 b = *(const f32x4*)(A1 + i);
#pragma unroll
  for (int j = 0; j < 4; j++) AO[i + j] = (__bf16)((a[j] + b[j]) * inv);
}

// ---------------------------------------------------------------------------

extern "C" void kernel_launch(void* const* d_in, const int* in_sizes, int n_in,
                              void* d_out, int out_size, void* d_ws, size_t ws_size,
                              hipStream_t stream) {
  const float* hidden = (const float*)d_in[0];
  const float* cosT   = (const float*)d_in[1];
  const float* sinT   = (const float*)d_in[2];
  // d_in[3] = mask (pure causal, computed analytically), d_in[4] = arange (unused)
  const float* WAq = (const float*)d_in[5];
  const float* WAk = (const float*)d_in[6];
  const float* WAv = (const float*)d_in[7];
  const float* WBq = (const float*)d_in[8];
  const float* WBk = (const float*)d_in[9];
  const float* WBv = (const float*)d_in[10];
  const float* Wo  = (const float*)d_in[11];
  float* out = (float*)d_out;

  // Workspace layout (lifetime-aliased, proven R3..R9), ~67.9 MB:
  //   [0)          hid_bf (8.39M)  -> AOf0 (16.78M) after build_qkv is done
  //   [8388608)    WallT  (5.77M)      (overlaid by AOf0)
  //   [14155776)   Pproj  (11.53M)     (first 2.6M overlaid by AOf0)
  //   [25690112)   WoT    (8.39M)      (live until final GEMM)
  //   [34078720)   Qb     (8.39M)  -> AO bf16 after attn is done
  //   [42467328)   Kb     (4.19M)
  //   [46661632)   Vt     (4.19M)
  //   [50855936)   AOf1   (16.78M)
  //   [67633152)   Ls     (0.26M)
  char* ws = (char*)d_ws;
  __bf16* hid_bf = (__bf16*)(ws);
  __bf16* WallT  = (__bf16*)(ws + 8388608);
  float*  Pproj  = (float*)(ws + 14155776);
  __bf16* WoT    = (__bf16*)(ws + 25690112);
  __bf16* Qb     = (__bf16*)(ws + 34078720);
  __bf16* Kb     = (__bf16*)(ws + 42467328);
  __bf16* Vt     = (__bf16*)(ws + 46661632);
  float*  AOf0   = (float*)(ws);
  float*  AOf1   = (float*)(ws + 50855936);
  float*  Ls     = (float*)(ws + 67633152);
  __bf16* AO     = (__bf16*)(ws + 34078720);  // aliases Qb (dead after attn)

  // prep: 2048 cvt blocks + 44*64 wall-transpose + 64*64 wo-transpose
  k_prep<<<2048 + 44 * 64 + 64 * 64, 256, 0, stream>>>(
      hidden, WAq, WAk, WAv, WBq, WBk, WBv, Wo, hid_bf, WallT, WoT);
  k_gemm_bt<<<dim3(NCOLS / 64, SEQ / 128), 256, 0, stream>>>(hid_bf, WallT, Pproj,
                                                             SEQ, NCOLS, HIDN);
  k_build_qkv<<<SEQ, 128, 0, stream>>>(Pproj, cosT, sinT, Qb, Kb, Vt);
  k_attn<<<1024, 256, 0, stream>>>(Qb, Kb, Vt, AOf0, AOf1, Ls);
  k_norm<<<(SEQ * HIDN / 4) / 256, 256, 0, stream>>>(AOf0, AOf1, Ls, AO);
  k_gemm_bt<<<dim3(HIDN / 64, SEQ / 128), 256, 0, stream>>>(AO, WoT, out,
                                                            SEQ, HIDN, HIDN);
}

// Round 11
// 160.841 us; speedup vs baseline: 1.1210x; 1.1210x over previous
//
#include <hip/hip_runtime.h>

// ---------------------------------------------------------------------------
// TPA attention, factorized to GQA flash attention.
// B=1, S=2048, HID=2048, H=16, KVH=8, D=128, QR=6, KR=2, VR=2
// ---------------------------------------------------------------------------

constexpr int SEQ   = 2048;
constexpr int HIDN  = 2048;
constexpr int NHEAD = 16;
constexpr int NKVH  = 8;
constexpr int DH    = 128;
constexpr int NCOLS = 1408;   // 96 Aq | 16 Ak | 16 Av | 768 Bq | 256 Bk | 256 Bv

typedef __bf16 bf16x8 __attribute__((ext_vector_type(8)));
typedef float  f32x4  __attribute__((ext_vector_type(4)));

#define MFMA(a, b, c) __builtin_amdgcn_mfma_f32_16x16x32_bf16((a), (b), (c), 0, 0, 0)

__device__ __forceinline__ void gload_lds16(const void* g, void* l) {
  __builtin_amdgcn_global_load_lds(
      (const __attribute__((address_space(1))) void*)g,
      (__attribute__((address_space(3))) void*)l, 16, 0, 0);
}

// ---- fused prep: hidden cvt + W_all^T transpose + Wo^T transpose ----------

__global__ __launch_bounds__(256) void k_prep(
    const float* __restrict__ hidden,
    const float* __restrict__ WAq, const float* __restrict__ WAk,
    const float* __restrict__ WAv, const float* __restrict__ WBq,
    const float* __restrict__ WBk, const float* __restrict__ WBv,
    const float* __restrict__ Wo,
    __bf16* __restrict__ hid_bf, __bf16* __restrict__ WT,
    __bf16* __restrict__ WoT) {
  const int bid = blockIdx.x;
  if (bid < 2048) {                       // ---- hidden f32 -> bf16, x8
    const int i = (bid * 256 + threadIdx.x) * 8;
    f32x4 a = *(const f32x4*)(hidden + i);
    f32x4 b = *(const f32x4*)(hidden + i + 4);
    bf16x8 v;
#pragma unroll
    for (int j = 0; j < 4; j++) { v[j] = (__bf16)a[j]; v[4 + j] = (__bf16)b[j]; }
    *(bf16x8*)(hid_bf + i) = v;
  } else if (bid < 2048 + 44 * 64) {      // ---- W_all^T [1408][2048]
    const int t = bid - 2048;
    const int bc = (t % 44) * 32, bk = (t / 44) * 32;
    __shared__ float tl[32][33];
    const int tx = threadIdx.x & 31, ty = threadIdx.x >> 5;  // ty 0..7
    const int c = bc + tx;
#pragma unroll
    for (int j = 0; j < 32; j += 8) {
      const int k = bk + ty + j;
      float v;
      if (c < 96)        v = WAq[k * 96 + c];
      else if (c < 112)  v = WAk[k * 16 + (c - 96)];
      else if (c < 128)  v = WAv[k * 16 + (c - 112)];
      else if (c < 896)  v = WBq[k * 768 + (c - 128)];
      else if (c < 1152) v = WBk[k * 256 + (c - 896)];
      else               v = WBv[k * 256 + (c - 1152)];
      tl[ty + j][tx] = v;                 // tl[k-local][c-local]
    }
    __syncthreads();
#pragma unroll
    for (int j = 0; j < 32; j += 8)
      WT[(size_t)(bc + ty + j) * HIDN + bk + tx] = (__bf16)tl[tx][ty + j];
  } else {                                // ---- Wo^T [2048][2048]
    const int t = bid - (2048 + 44 * 64);
    const int bn = (t % 64) * 32, bk = (t / 64) * 32;
    __shared__ float tl[32][33];
    const int tx = threadIdx.x & 31, ty = threadIdx.x >> 5;
#pragma unroll
    for (int j = 0; j < 32; j += 8)
      tl[ty + j][tx] = Wo[(size_t)(bk + ty + j) * HIDN + bn + tx];
    __syncthreads();
#pragma unroll
    for (int j = 0; j < 32; j += 8)
      WoT[(size_t)(bn + ty + j) * HIDN + bk + tx] = (__bf16)tl[tx][ty + j];
  }
}

// ---- GEMM: C[M][N] = A[M][K] * BT[N][K]^T, bf16 in, f32 out ---------------
// 128(M)x64(N) tile, 4 waves (2x2), BK=32, 4-deep counted-vmcnt pipeline.
// 2D XCD region swizzle when divisible (out GEMM 32x16); else chunk swizzle.

__global__ __launch_bounds__(256) void k_gemm_bt(const __bf16* __restrict__ A,
                                                 const __bf16* __restrict__ BT,
                                                 float* __restrict__ C,
                                                 int M, int N, int K) {
  __shared__ __bf16 As[4][4096];  // [buf][128 rows][32 k] linear
  __shared__ __bf16 Bs[4][2048];  // [buf][64 cols][32 k] linear
  const int tid = threadIdx.x;
  const int w = tid >> 6, lane = tid & 63;
  const int lhi = lane >> 4, llo = lane & 15;
  const int wr = w >> 1, wc = w & 1;

  const int nx = gridDim.x, ny = gridDim.y;
  const int id = blockIdx.y * nx + blockIdx.x;
  int brow, bcol;
  if (((ny & 1) == 0) && ((nx & 3) == 0)) {
    // 2D region per XCD: (ny/2) rows x (nx/4) cols
    const int g = id & 7, k = id >> 3;
    const int rows = ny >> 1, cols = nx >> 2;
    const int rg = g >> 2, cg = g & 3;
    const int r = k % rows, c = k / rows;
    brow = (rg * rows + r) * 128;
    bcol = (cg * cols + c) * 64;
  } else {
    const int cpx = (nx * ny) >> 3;
    const int sid = (id & 7) * cpx + (id >> 3);
    brow = (sid / nx) * 128;
    bcol = (sid % nx) * 64;
  }

  const int rA = lane >> 2, kA = (lane & 3) * 8;  // lane -> (row-in-seg, k-seg)
  const int nt = K >> 5;

  f32x4 acc[4][2];
#pragma unroll
  for (int m = 0; m < 4; m++)
#pragma unroll
    for (int n = 0; n < 2; n++) acc[m][n] = (f32x4){0.f, 0.f, 0.f, 0.f};

  auto stage = [&](int t) {              // 3 gload_lds per wave
    const int buf = t & 3;
    const int k0 = t * 32;
#pragma unroll
    for (int i = 0; i < 2; i++) {
      int seg = w * 2 + i;               // 8 segs of 1KB for A
      int row = seg * 16 + rA;
      gload_lds16(A + (size_t)(brow + row) * K + k0 + kA, &As[buf][seg * 512]);
    }
    gload_lds16(BT + (size_t)(bcol + w * 16 + rA) * K + k0 + kA, &Bs[buf][w * 512]);
  };

  stage(0); stage(1); stage(2);                      // nt >= 4 always here
  asm volatile("s_waitcnt vmcnt(6)" ::: "memory");   // tile 0 landed
  __builtin_amdgcn_s_barrier();

  for (int t = 0; t < nt; t++) {
    if (t + 3 < nt) stage(t + 3);
    const int buf = t & 3;
    bf16x8 af[4], bfr[2];
#pragma unroll
    for (int m = 0; m < 4; m++)
      af[m] = *(const bf16x8*)&As[buf][(wr * 64 + m * 16 + llo) * 32 + lhi * 8];
#pragma unroll
    for (int n = 0; n < 2; n++)
      bfr[n] = *(const bf16x8*)&Bs[buf][(wc * 32 + n * 16 + llo) * 32 + lhi * 8];
#pragma unroll
    for (int m = 0; m < 4; m++)
#pragma unroll
      for (int n = 0; n < 2; n++) acc[m][n] = MFMA(af[m], bfr[n], acc[m][n]);
    const int rem = nt - 2 - t;          // stages in flight beyond t+1
    if (rem >= 2)      asm volatile("s_waitcnt vmcnt(6)" ::: "memory");
    else if (rem == 1) asm volatile("s_waitcnt vmcnt(3)" ::: "memory");
    else               asm volatile("s_waitcnt vmcnt(0)" ::: "memory");
    __builtin_amdgcn_s_barrier();
  }

#pragma unroll
  for (int m = 0; m < 4; m++)
#pragma unroll
    for (int n = 0; n < 2; n++) {
      int r0 = brow + wr * 64 + m * 16 + lhi * 4;
      int c0 = bcol + wc * 32 + n * 16 + llo;
#pragma unroll
      for (int r = 0; r < 4; r++) C[(size_t)(r0 + r) * N + c0] = acc[m][n][r];
    }
}

// ---- build Q/K/Vt from projections (rope + rank contraction) --------------

__global__ __launch_bounds__(128) void k_build_qkv(const float* __restrict__ P,
                                                   const float* __restrict__ cosT,
                                                   const float* __restrict__ sinT,
                                                   __bf16* __restrict__ Qo,
                                                   __bf16* __restrict__ Ko,
                                                   __bf16* __restrict__ Vto) {
  const int q = blockIdx.x, d = threadIdx.x;  // 128 threads
  __shared__ float Ash[128];                  // Aq(96) | Ak(16) | Av(16)
  const float* row = P + (size_t)q * NCOLS;
  Ash[d] = row[d];
  __syncthreads();
  const int m2 = (d >> 1) * 2;
  const bool odd = d & 1;
  const float c = cosT[q * 64 + (d >> 1)];
  const float s = sinT[q * 64 + (d >> 1)];

  float qacc[16];
#pragma unroll
  for (int h = 0; h < 16; h++) qacc[h] = 0.f;
#pragma unroll
  for (int r = 0; r < 6; r++) {
    float xe = row[128 + r * 128 + m2];
    float xo = row[128 + r * 128 + m2 + 1];
    float br = odd ? (xe * s + xo * c) : (xe * c - xo * s);
#pragma unroll
    for (int h = 0; h < 16; h++) qacc[h] += Ash[h * 6 + r] * br;
  }
#pragma unroll
  for (int h = 0; h < 16; h++)
    Qo[((size_t)h * SEQ + q) * DH + d] = (__bf16)(qacc[h] * 0.08838834764831845f);

  float kacc[8];
#pragma unroll
  for (int g = 0; g < 8; g++) kacc[g] = 0.f;
#pragma unroll
  for (int ss = 0; ss < 2; ss++) {
    float xe = row[896 + ss * 128 + m2];
    float xo = row[896 + ss * 128 + m2 + 1];
    float bs = odd ? (xe * s + xo * c) : (xe * c - xo * s);
#pragma unroll
    for (int g = 0; g < 8; g++) kacc[g] += Ash[96 + g * 2 + ss] * bs;
  }
#pragma unroll
  for (int g = 0; g < 8; g++)
    Ko[((size_t)g * SEQ + q) * DH + d] = (__bf16)kacc[g];

  float vacc[8];
#pragma unroll
  for (int g = 0; g < 8; g++) vacc[g] = 0.f;
#pragma unroll
  for (int u = 0; u < 2; u++) {
    float vu = row[1152 + u * 128 + d];
#pragma unroll
    for (int g = 0; g < 8; g++) vacc[g] += Ash[112 + g * 2 + u] * vu;
  }
#pragma unroll
  for (int g = 0; g < 8; g++)
    Vto[((size_t)g * DH + d) * SEQ + q] = (__bf16)vacc[g];
}

// ---- flash attention, split-KV parts=2, LDS-staged, XCD-affine ------------
// R6 decode restored (proven 55.5µs): heavy-first per XCD stripe is the
// correct greedy under dynamic backfill scheduling (R10's "static CU slot"
// balanced decode regressed — dispatch isn't statically assigned).

__global__ __launch_bounds__(256) void k_attn(const __bf16* __restrict__ Q,
                                              const __bf16* __restrict__ Kc,
                                              const __bf16* __restrict__ Vt,
                                              float* __restrict__ AOf0,
                                              float* __restrict__ AOf1,
                                              float* __restrict__ Ls) {
  const int raw = blockIdx.x;          // 0..1023
  const int g = raw & 7;               // XCD affinity
  const int j = raw >> 3;              // 0..127
  const int bqi = 31 - (j >> 2);       // heavy-first per XCD stripe
  const int hh = (j >> 1) & 1;
  const int p = j & 1;
  const int h = g * 2 + hh;
  const int w = threadIdx.x >> 6, lane = threadIdx.x & 63;
  const int lhi = lane >> 4, llo = lane & 15;
  const int q0 = bqi * 64 + w * 16;
  const int t0 = p * (bqi + 1), t1 = t0 + bqi + 1;  // half the causal tiles

  __shared__ __bf16 KVs[2][8192];    // 8KB K (32x128 swz) | 8KB V (128x32 swz)
  __shared__ __bf16 Plds[4][512];    // per-wave 16x32 P tile, swizzled

  const __bf16* Qh = Q  + (size_t)h * SEQ * DH;
  const __bf16* Kg = Kc + (size_t)g * SEQ * DH;
  const __bf16* Vg = Vt + (size_t)g * DH * SEQ;
  __bf16* Pl = Plds[w];
  float* AOc = p ? AOf1 : AOf0;

  bf16x8 aq[4];
#pragma unroll
  for (int c = 0; c < 4; c++)
    aq[c] = *(const bf16x8*)&Qh[(size_t)(q0 + llo) * DH + c * 32 + lhi * 8];

  f32x4 oacc[8];
  float lsum[4] = {0.f, 0.f, 0.f, 0.f};
#pragma unroll
  for (int n = 0; n < 8; n++) oacc[n] = (f32x4){0.f, 0.f, 0.f, 0.f};

  // stage one 32-key tile: waves 0-1 stage K (512 16B chunks, swizzled
  // source so linear LDS dest + swizzled read match), waves 2-3 stage V.
  auto stage = [&](int kb, int buf) {
    __bf16* L = KVs[buf];
    if (w < 2) {
#pragma unroll
      for (int u = 0; u < 4; u++) {
        int c = w * 256 + u * 64 + lane;
        int row = c >> 4, jj = c & 15;
        gload_lds16(Kg + (size_t)(kb + row) * DH + ((jj ^ (row & 7)) * 8),
                    L + (w * 256 + u * 64) * 8);
      }
    } else {
#pragma unroll
      for (int u = 0; u < 4; u++) {
        int c = (w - 2) * 256 + u * 64 + lane;
        int d = c >> 2, jj = c & 3;
        gload_lds16(Vg + (size_t)d * SEQ + kb + ((jj ^ ((d >> 1) & 3)) * 8),
                    L + 4096 + ((w - 2) * 256 + u * 64) * 8);
      }
    }
  };

  stage(t0 * 32, t0 & 1);
  for (int t = t0; t < t1; t++) {
    const int kb = t * 32;
    const int buf = t & 1;
    if (t + 1 < t1) {
      stage(kb + 32, buf ^ 1);
      asm volatile("s_waitcnt vmcnt(4)" ::: "memory");  // cur tile staged
    } else {
      asm volatile("s_waitcnt vmcnt(0)" ::: "memory");
    }
    __builtin_amdgcn_s_barrier();
    if (kb <= q0 + 15) {   // wave-uniform skip of fully-masked tiles
      const __bf16* Kl = KVs[buf];
      const __bf16* Vl = KVs[buf] + 4096;
      f32x4 s0 = {0.f, 0.f, 0.f, 0.f}, s1 = {0.f, 0.f, 0.f, 0.f};
#pragma unroll
      for (int c = 0; c < 4; c++) {
        const int row0 = llo, row1 = 16 + llo;
        bf16x8 k0 = *(const bf16x8*)((const char*)Kl + row0 * 256 +
                                     ((c * 64 + lhi * 16) ^ ((row0 & 7) << 4)));
        bf16x8 k1 = *(const bf16x8*)((const char*)Kl + row1 * 256 +
                                     ((c * 64 + lhi * 16) ^ ((row1 & 7) << 4)));
        s0 = MFMA(aq[c], k0, s0);
        s1 = MFMA(aq[c], k1, s1);
      }
#pragma unroll
      for (int r = 0; r < 4; r++) {
        const int qrow = q0 + lhi * 4 + r;
        const int rho = lhi * 4 + r;
        // w = exp(50*tanh(v/50)) = exp2(72.135 - 144.27/(e^{v/25}+1));
        // range [e^-50, e^50] — f32-safe, exact softmax after normalize.
        float t0e = exp2f(s0[r] * 0.057707802f);
        float t1e = exp2f(s1[r] * 0.057707802f);
        float p0 = exp2f(72.134752f - 144.269504f * __builtin_amdgcn_rcpf(t0e + 1.f));
        float p1 = exp2f(72.134752f - 144.269504f * __builtin_amdgcn_rcpf(t1e + 1.f));
        if (kb + llo > qrow) p0 = 0.f;
        if (kb + 16 + llo > qrow) p1 = 0.f;
        lsum[r] += p0 + p1;
        const int sw = ((rho >> 1) & 3) << 4;
        *(__bf16*)((char*)Pl + rho * 64 + ((llo * 2) ^ sw))      = (__bf16)p0;
        *(__bf16*)((char*)Pl + rho * 64 + ((llo * 2 + 32) ^ sw)) = (__bf16)p1;
      }
      bf16x8 pa = *(const bf16x8*)((const char*)Pl + llo * 64 +
                                   ((lhi * 16) ^ (((llo >> 1) & 3) << 4)));
#pragma unroll
      for (int n = 0; n < 8; n++) {
        const int d = n * 16 + llo;
        bf16x8 vf = *(const bf16x8*)((const char*)Vl + d * 64 +
                                     ((lhi * 16) ^ (((d >> 1) & 3) << 4)));
        oacc[n] = MFMA(pa, vf, oacc[n]);
      }
    }
    asm volatile("" ::: "memory");
    __builtin_amdgcn_s_barrier();
  }

#pragma unroll
  for (int r = 0; r < 4; r++) {
    float tsum = lsum[r];
    tsum += __shfl_xor(tsum, 1);
    tsum += __shfl_xor(tsum, 2);
    tsum += __shfl_xor(tsum, 4);
    tsum += __shfl_xor(tsum, 8);
    const int qrow = q0 + lhi * 4 + r;
    if (llo == 0) Ls[((size_t)p * NHEAD + h) * SEQ + qrow] = tsum;
#pragma unroll
    for (int n = 0; n < 8; n++)
      AOc[(size_t)qrow * HIDN + h * DH + n * 16 + llo] = oacc[n][r];
  }
}

// ---- merge split-KV partials, normalize, cast to bf16 ---------------------
// Kept as a separate pass deliberately: it compacts 33.5MB f32 partials into
// 8.4MB bf16 A-panel for the out-GEMM — fusing it into the GEMM would make
// the GEMM re-read the f32 partials per column-block (3x A-side traffic).

__global__ __launch_bounds__(256) void k_norm(const float* __restrict__ A0,
                                              const float* __restrict__ A1,
                                              const float* __restrict__ Ls,
                                              __bf16* __restrict__ AO) {
  const int i = (blockIdx.x * 256 + threadIdx.x) * 4;  // 4M elems, f32x4
  const int q = i >> 11, h = (i & 2047) >> 7;
  const float inv = 1.f / (Ls[h * SEQ + q] + Ls[(NHEAD + h) * SEQ + q]);
  f32x4 a = *(const f32x4*)(A0 + i);
  f32x4 b = *(const f32x4*)(A1 + i);
#pragma unroll
  for (int j = 0; j < 4; j++) AO[i + j] = (__bf16)((a[j] + b[j]) * inv);
}

// ---------------------------------------------------------------------------

extern "C" void kernel_launch(void* const* d_in, const int* in_sizes, int n_in,
                              void* d_out, int out_size, void* d_ws, size_t ws_size,
                              hipStream_t stream) {
  const float* hidden = (const float*)d_in[0];
  const float* cosT   = (const float*)d_in[1];
  const float* sinT   = (const float*)d_in[2];
  // d_in[3] = mask (pure causal, computed analytically), d_in[4] = arange (unused)
  const float* WAq = (const float*)d_in[5];
  const float* WAk = (const float*)d_in[6];
  const float* WAv = (const float*)d_in[7];
  const float* WBq = (const float*)d_in[8];
  const float* WBk = (const float*)d_in[9];
  const float* WBv = (const float*)d_in[10];
  const float* Wo  = (const float*)d_in[11];
  float* out = (float*)d_out;

  // Workspace layout (lifetime-aliased, proven R3..R9), ~67.9 MB:
  //   [0)          hid_bf (8.39M)  -> AOf0 (16.78M) after build_qkv is done
  //   [8388608)    WallT  (5.77M)      (overlaid by AOf0)
  //   [14155776)   Pproj  (11.53M)     (first 2.6M overlaid by AOf0)
  //   [25690112)   WoT    (8.39M)      (live until final GEMM)
  //   [34078720)   Qb     (8.39M)  -> AO bf16 after attn is done
  //   [42467328)   Kb     (4.19M)
  //   [46661632)   Vt     (4.19M)
  //   [50855936)   AOf1   (16.78M)
  //   [67633152)   Ls     (0.26M)
  char* ws = (char*)d_ws;
  __bf16* hid_bf = (__bf16*)(ws);
  __bf16* WallT  = (__bf16*)(ws + 8388608);
  float*  Pproj  = (float*)(ws + 14155776);
  __bf16* WoT    = (__bf16*)(ws + 25690112);
  __bf16* Qb     = (__bf16*)(ws + 34078720);
  __bf16* Kb     = (__bf16*)(ws + 42467328);
  __bf16* Vt     = (__bf16*)(ws + 46661632);
  float*  AOf0   = (float*)(ws);
  float*  AOf1   = (float*)(ws + 50855936);
  float*  Ls     = (float*)(ws + 67633152);
  __bf16* AO     = (__bf16*)(ws + 34078720);  // aliases Qb (dead after attn)

  // prep: 2048 cvt blocks + 44*64 wall-transpose + 64*64 wo-transpose
  k_prep<<<2048 + 44 * 64 + 64 * 64, 256, 0, stream>>>(
      hidden, WAq, WAk, WAv, WBq, WBk, WBv, Wo, hid_bf, WallT, WoT);
  k_gemm_bt<<<dim3(NCOLS / 64, SEQ / 128), 256, 0, stream>>>(hid_bf, WallT, Pproj,
                                                             SEQ, NCOLS, HIDN);
  k_build_qkv<<<SEQ, 128, 0, stream>>>(Pproj, cosT, sinT, Qb, Kb, Vt);
  k_attn<<<1024, 256, 0, stream>>>(Qb, Kb, Vt, AOf0, AOf1, Ls);
  k_norm<<<(SEQ * HIDN / 4) / 256, 256, 0, stream>>>(AOf0, AOf1, Ls, AO);
  k_gemm_bt<<<dim3(HIDN / 64, SEQ / 128), 256, 0, stream>>>(AO, WoT, out,
                                                            SEQ, HIDN, HIDN);
}